// Round 12
// baseline (289.123 us; speedup 1.0000x reference)
//
#include <hip/hip_runtime.h>
#include <hip/hip_bf16.h>

// Problem constants: N=50000, E=600000, F=128, H=128, O=64, R=8
#define F_DIM 128
#define H_DIM 128
#define O_DIM 64
#define R_NUM 8

typedef __attribute__((ext_vector_type(8))) short bf16x8;
typedef __attribute__((ext_vector_type(4))) float f32x4;
typedef __attribute__((ext_vector_type(8))) unsigned short u16x8;

union V8 { bf16x8 v; short4 h[2]; };

__device__ __forceinline__ unsigned short f2b(float f) {
    unsigned u = __float_as_uint(f);
    u += 0x7FFFu + ((u >> 16) & 1u);   // RNE (manual; kept for fill2 only)
    return (unsigned short)(u >> 16);
}
// HW RNE pair-convert (v_cvt_pk_bf16_f32), bit-identical to manual RNE.
__device__ __forceinline__ unsigned f2b2(float lo, float hi) {
    union { __hip_bfloat162 h; unsigned u; } p;
    p.h = __float22bfloat162_rn(make_float2(lo, hi));
    return p.u;
}
__device__ __forceinline__ unsigned short f2b1(float f) {
    union { __hip_bfloat16 h; unsigned short u; } p;
    p.h = __float2bfloat16(f);
    return p.u;
}
__device__ __forceinline__ float b2f(unsigned short b) {
    return __uint_as_float(((unsigned)b) << 16);
}

// ---- fused setup A: (dst,rel) degree count + per-block ew min/max ;
//      x -> bf16 ; both weight stacks transpose+convert. Grid MUST be 512. ----
__global__ __launch_bounds__(256) void setupA(
    const float* __restrict__ ew, const int* __restrict__ dst,
    const int* __restrict__ et, int E, int* __restrict__ deg2,
    float* __restrict__ bmn, float* __restrict__ bmx,
    const float* __restrict__ x, unsigned short* __restrict__ xb, long x4,
    const float* __restrict__ W1, const float* __restrict__ root1,
    const float* __restrict__ W2, const float* __restrict__ root2,
    unsigned short* __restrict__ wt1, unsigned short* __restrict__ wt2) {
    __shared__ float smn[256], smx[256];
    const int tid = threadIdx.x;
    const int gstride = gridDim.x * blockDim.x;
    int g0 = blockIdx.x * blockDim.x + tid;

    float mn = 1e30f, mx = -1e30f;
    for (int i = g0; i < E; i += gstride) {
        atomicAdd(&deg2[dst[i] * R_NUM + et[i]], 1);
        float v = ew[i];
        mn = fminf(mn, v);
        mx = fmaxf(mx, v);
    }
    smn[tid] = mn; smx[tid] = mx;
    __syncthreads();
    for (int s = 128; s > 0; s >>= 1) {
        if (tid < s) {
            smn[tid] = fminf(smn[tid], smn[tid + s]);
            smx[tid] = fmaxf(smx[tid], smx[tid + s]);
        }
        __syncthreads();
    }
    if (tid == 0) { bmn[blockIdx.x] = smn[0]; bmx[blockIdx.x] = smx[0]; }

    for (long i = g0; i < x4; i += gstride) {
        float4 v = ((const float4*)x)[i];
        uint2 o = make_uint2(f2b2(v.x, v.y), f2b2(v.z, v.w));
        ((uint2*)xb)[i] = o;
    }

    const int n1 = 9 * 128 * 128, n2 = 9 * 64 * 128;
    for (int idx = g0; idx < n1 + n2; idx += gstride) {
        if (idx < n1) {
            int r = idx / (128 * 128), rem = idx % (128 * 128);
            int n = rem / 128, k = rem % 128;
            float v = (r < 8) ? W1[((size_t)r * 128 + k) * 128 + n]
                              : root1[(size_t)k * 128 + n];
            wt1[idx] = f2b1(v);
        } else {
            int j = idx - n1;
            int r = j / (64 * 128), rem = j % (64 * 128);
            int n = rem / 128, k = rem % 128;
            float v = (r < 8) ? W2[((size_t)r * 128 + k) * 64 + n]
                              : root2[(size_t)k * 64 + n];
            wt2[j] = f2b1(v);
        }
    }
}

// ---- scan1: per-2048-chunk exclusive scan of deg2 + fused invc ----
__global__ void scan1_kernel(const int* __restrict__ deg, int* __restrict__ rp,
                             int* __restrict__ bsum, float* __restrict__ invc,
                             int M, int N) {
    __shared__ int s[256];
    int base = blockIdx.x * 2048;
    int t = threadIdx.x;
    int v[8]; int loc = 0;
#pragma unroll
    for (int i = 0; i < 8; ++i) {
        int idx = base + t * 8 + i;
        v[i] = (idx < M) ? deg[idx] : 0;
        loc += v[i];
    }
    int node = blockIdx.x * 256 + t;
    if (node < N) invc[node] = 1.0f / (float)max(loc, 1);
    s[t] = loc;
    __syncthreads();
    for (int off = 1; off < 256; off <<= 1) {
        int x = (t >= off) ? s[t - off] : 0;
        __syncthreads();
        s[t] += x;
        __syncthreads();
    }
    int run = s[t] - loc;
#pragma unroll
    for (int i = 0; i < 8; ++i) {
        int idx = base + t * 8 + i;
        if (idx < M) rp[idx] = run;
        run += v[i];
    }
    if (t == 255) bsum[blockIdx.x] = s[255];
}

// ---- scan2 + global min/max reduce (single block) ----
// After this, rp2 stays CHUNK-LOCAL; consumers add bsum[i>>11].
__global__ void scan2_mm(int* bsum, int nb, const float* __restrict__ bmn,
                         const float* __restrict__ bmx, float* mm) {
    __shared__ int s[256];
    __shared__ float smn[256], smx[256];
    int t = threadIdx.x;
    int v = (t < nb) ? bsum[t] : 0;
    s[t] = v;
    smn[t] = fminf(bmn[t], bmn[t + 256]);
    smx[t] = fmaxf(bmx[t], bmx[t + 256]);
    __syncthreads();
    for (int off = 1; off < 256; off <<= 1) {
        int x = (t >= off) ? s[t - off] : 0;
        __syncthreads();
        s[t] += x;
        __syncthreads();
    }
    if (t < nb) bsum[t] = s[t] - v;
    for (int r = 128; r > 0; r >>= 1) {
        if (t < r) {
            smn[t] = fminf(smn[t], smn[t + r]);
            smx[t] = fmaxf(smx[t], smx[t + r]);
        }
        __syncthreads();
    }
    if (t == 0) { mm[0] = smn[0]; mm[1] = smx[0]; }
}

// ---- CSR fill: pos = (rp2[i]++ local) + bsum[i>>11] ;
//      erec = bf16(w_norm * invc[dst])<<17 | src   (4B record)
__global__ void fill2_kernel(const int* __restrict__ src, const int* __restrict__ dst,
                             const int* __restrict__ et, const float* __restrict__ ew,
                             const float* __restrict__ mm, const float* __restrict__ invc,
                             int* __restrict__ rp2, const int* __restrict__ bsum,
                             unsigned* __restrict__ erec, int E) {
    int e = blockIdx.x * blockDim.x + threadIdx.x;
    if (e >= E) return;
    int d = dst[e];
    int i = d * R_NUM + et[e];
    int pos = atomicAdd(&rp2[i], 1) + bsum[i >> 11];
    float mn = mm[0], mx = mm[1];
    unsigned wq = f2b((ew[e] - mn) / (mx - mn + 1e-8f) * invc[d]);
    erec[pos] = (wq << 17) | (unsigned)src[e];
}

// ---- gather (layer 1): y[r][n] = sum_{e in seg(n,r)} w_premul * inp[src]
//      y layout R-MAJOR [r][N][128]. Epilogue uses HW cvt_pk. ----
__global__ __launch_bounds__(256) void gather_y(
    const int* __restrict__ rp2, const int* __restrict__ bsum,
    const unsigned* __restrict__ erec,
    const unsigned short* __restrict__ inp,
    unsigned short* __restrict__ y, int N) {
    int gid = blockIdx.x * 256 + threadIdx.x;
    int seg = gid >> 4;
    int n = seg >> 3;
    if (n >= N) return;
    int j = (gid & 15) * 8;
    int beg = (seg == 0) ? 0 : rp2[seg - 1] + bsum[(seg - 1) >> 11];
    int end = rp2[seg] + bsum[seg >> 11];
    float acc[8] = {0.f, 0.f, 0.f, 0.f, 0.f, 0.f, 0.f, 0.f};
    int k = beg;
    for (; k + 2 <= end; k += 2) {
        unsigned r0 = erec[k], r1 = erec[k + 1];
        float w0 = __uint_as_float((r0 >> 1) & 0x7FFF8000u);
        float w1 = __uint_as_float((r1 >> 1) & 0x7FFF8000u);
        u16x8 v0 = *(const u16x8*)(inp + (size_t)(r0 & 0x1FFFFu) * 128 + j);
        u16x8 v1 = *(const u16x8*)(inp + (size_t)(r1 & 0x1FFFFu) * 128 + j);
#pragma unroll
        for (int c = 0; c < 8; ++c) acc[c] += w0 * b2f(v0[c]);
#pragma unroll
        for (int c = 0; c < 8; ++c) acc[c] += w1 * b2f(v1[c]);
    }
    if (k < end) {
        unsigned r0 = erec[k];
        float w0 = __uint_as_float((r0 >> 1) & 0x7FFF8000u);
        u16x8 v0 = *(const u16x8*)(inp + (size_t)(r0 & 0x1FFFFu) * 128 + j);
#pragma unroll
        for (int c = 0; c < 8; ++c) acc[c] += w0 * b2f(v0[c]);
    }
    uint4 ov = make_uint4(f2b2(acc[0], acc[1]), f2b2(acc[2], acc[3]),
                          f2b2(acc[4], acc[5]), f2b2(acc[6], acc[7]));
    // r-major: y[(seg&7)*N + n]
    *(uint4*)(y + ((size_t)(seg & 7) * N + (size_t)n) * 128 + j) = ov;
}

// =====================================================================
// gemm_y2 (layer 1, FAT TILE + 2-DEEP REGISTER PREFETCH): out =
// sum_r y[r][n]@Wt[r] + inp@Wt[8] + bias. 128 nodes/block, 512 threads
// (8 waves); wave w owns output cols w*16..+15 x all 128 nodes.
// A-fragments straight from L2-resident wt1. y-tile LDS double-buffered
// with RAW s_barrier — UNCHANGED sync topology vs the passing round-7/11
// structure. NEW: two register staging sets (stA/stB) so tile r+2's
// global loads are issued at iteration r — 2 barriers of HBM-latency
// hiding instead of 1 (y-read was ~2.5x above its 16us BW floor,
// latency-bound at depth 1). +32 VGPR (~92 total, < 128 budget @ 8
// waves). Register WAR safe: ds_write(st) precedes issue(r+2) in
// program order; operands read at issue.
// LDS race check (unchanged): buf[r&1] rewritten at iter r+2, after
// barrier(r+1); all iter-r reads of buf[r&1] completed before each wave
// reached barrier(r+1).
// =====================================================================
__global__ __launch_bounds__(512, 4) void gemm_y2(
    const unsigned short* __restrict__ y,        // 8 x N x 128 bf16 (r-major)
    const unsigned short* __restrict__ inp,      // xb: N x 128 bf16
    const unsigned short* __restrict__ Wt,       // 9 x 128 x 128 bf16
    const float* __restrict__ bias,
    unsigned short* __restrict__ outb, int N)
{
    __shared__ unsigned short smem[2 * 128 * 132];   // 2 x (128 x 132) y bufs

    const int tid = threadIdx.x;
    const int w = tid >> 6, lane = tid & 63;         // w in 0..7
    const int quad = lane >> 4, l15 = lane & 15;
    const int n0 = blockIdx.x * 128;

    // per-thread staging slots: 4 chunks of 16B (128 rows x 16 segs / 512 thr)
    V8 stA[4], stB[4];
    int srow[4], sseg[4];
#pragma unroll
    for (int it = 0; it < 4; ++it) {
        int u = tid + it * 512;
        srow[it] = u >> 4;          // 0..127
        sseg[it] = u & 15;
    }

    // issue global loads for tile r into the given reg set (r==8 -> root/xb)
    auto issue = [&](int r, V8* st) {
#pragma unroll
        for (int it = 0; it < 4; ++it) {
            int node = n0 + srow[it];
            if (node >= N) node = N - 1;
            const unsigned short* src = (r < 8)
                ? y + ((size_t)r * N + (size_t)node) * 128 + sseg[it] * 8
                : inp + (size_t)node * 128 + sseg[it] * 8;
            st[it].v = *(const bf16x8*)src;
        }
    };

    f32x4 acc[8];
#pragma unroll
    for (int g = 0; g < 8; ++g) acc[g] = (f32x4){0.f, 0.f, 0.f, 0.f};

    issue(0, stA);
    issue(1, stB);

    for (int r = 0; r < 9; ++r) {
        V8* cur = (r & 1) ? stB : stA;
        unsigned short* ysb = smem + (r & 1) * (128 * 132);
        // write staged tile r to LDS (compiler waits vmcnt for cur deps)
#pragma unroll
        for (int it = 0; it < 4; ++it) {
            *(short4*)&ysb[srow[it] * 132 + sseg[it] * 8]     = cur[it].h[0];
            *(short4*)&ysb[srow[it] * 132 + sseg[it] * 8 + 4] = cur[it].h[1];
        }
        // 2-deep prefetch: tile r+2 into the just-freed reg set; these
        // loads stay in flight across TWO barriers
        if (r < 7) issue(r + 2, cur);
        // A-fragments (this wave's 16-col slice), straight from L2,
        // issued pre-barrier so latency overlaps barrier wait
        const unsigned short* wbase = Wt + (size_t)r * 128 * 128;
        bf16x8 afr[4];
#pragma unroll
        for (int k2 = 0; k2 < 4; ++k2) {
            afr[k2] = *(const bf16x8*)(wbase
                + (size_t)(w * 16 + l15) * 128 + k2 * 32 + quad * 8);
        }
        asm volatile("s_waitcnt lgkmcnt(0)" ::: "memory");
        __builtin_amdgcn_s_barrier();

#pragma unroll
        for (int k2 = 0; k2 < 4; ++k2) {
#pragma unroll
            for (int g = 0; g < 8; ++g) {
                const unsigned short* yr = ysb + (size_t)(g * 16 + l15) * 132
                                           + k2 * 32 + quad * 8;
                V8 b;
                b.h[0] = *(const short4*)yr;
                b.h[1] = *(const short4*)(yr + 4);
                acc[g] = __builtin_amdgcn_mfma_f32_16x16x32_bf16(afr[k2], b.v, acc[g], 0, 0, 0);
            }
        }
        // no trailing barrier: next iteration's ds_writes go to the other
        // buffer; overwrite of THIS buffer is 2 barriers away
    }

    __syncthreads();   // all MFMA reads done before stg overwrites smem
    unsigned short* stg = smem;   // 128 x 136 (34.8 KB, fits)
    {
        const int c0 = w * 16 + quad * 4;
        float4 bs = *(const float4*)(bias + c0);
#pragma unroll
        for (int g = 0; g < 8; ++g) {
            float v0 = acc[g][0] + bs.x, v1 = acc[g][1] + bs.y;
            float v2 = acc[g][2] + bs.z, v3 = acc[g][3] + bs.w;
            v0 = fmaxf(v0, 0.f); v1 = fmaxf(v1, 0.f);
            v2 = fmaxf(v2, 0.f); v3 = fmaxf(v3, 0.f);
            uint2 o = make_uint2(f2b2(v0, v1), f2b2(v2, v3));
            *(uint2*)&stg[(g * 16 + l15) * 136 + c0] = o;
        }
    }
    __syncthreads();
    const int gn = tid >> 2, gq = tid & 3;   // gn 0..127
    const int gnode = n0 + gn;
    if (gnode < N) {
        const unsigned short* srw = stg + gn * 136 + gq * 32;
        unsigned short* drow = outb + (size_t)gnode * 128 + gq * 32;
#pragma unroll
        for (int c = 0; c < 4; ++c)
            *(bf16x8*)(drow + c * 8) = *(const bf16x8*)(srw + c * 8);
    }
}

// =====================================================================
// gemm_proj2 (layer 2 transform-first, FAT TILE): proj2[r][n][c] =
// h[n] @ W2t[r], r=0..8 (r=8 = root). 128 nodes/block, 512 threads
// (8 waves); wave w owns nodes w*16..+15 x all 64 cols. (Round-11
// passing structure, unchanged.)
// =====================================================================
__global__ __launch_bounds__(512) void gemm_proj2(
    const unsigned short* __restrict__ h,     // N x 128 bf16
    const unsigned short* __restrict__ Wt,    // 9 x 64 x 128 bf16
    unsigned short* __restrict__ proj2,       // 9 x N x 64 bf16
    int N)
{
    __shared__ unsigned short hs[128 * 132];
    __shared__ unsigned short wsd[64 * 132];
    __shared__ unsigned short ts[8 * 16 * 68];   // per-wave private 16x68

    const int tid = threadIdx.x;
    const int w = tid >> 6, lane = tid & 63;     // w in 0..7
    const int quad = lane >> 4, l15 = lane & 15;
    const int n0 = blockIdx.x * 128;

    // stage h slice once (128 nodes x 128)
#pragma unroll
    for (int it = 0; it < 4; ++it) {
        int u = tid + it * 512;
        int row = u >> 4, seg = u & 15;
        int node = n0 + row;
        if (node >= N) node = N - 1;
        V8 v; v.v = *(const bf16x8*)(h + (size_t)node * 128 + seg * 8);
        *(short4*)&hs[row * 132 + seg * 8]     = v.h[0];
        *(short4*)&hs[row * 132 + seg * 8 + 4] = v.h[1];
    }

    for (int r = 0; r < 9; ++r) {
        // stage W2t[r] (64 rows x 128) with 512 threads (2 its)
#pragma unroll
        for (int it = 0; it < 2; ++it) {
            int u = tid + it * 512;
            int row = u >> 4, seg = u & 15;
            V8 v;
            v.v = *(const bf16x8*)(Wt + ((size_t)r * 64 + row) * 128 + seg * 8);
            *(short4*)&wsd[row * 132 + seg * 8]     = v.h[0];
            *(short4*)&wsd[row * 132 + seg * 8 + 4] = v.h[1];
        }
        __syncthreads();
        // MFMA: wave w -> nodes w*16..+15, 64 cols (NT=4)
        f32x4 acc[4];
#pragma unroll
        for (int nt = 0; nt < 4; ++nt) acc[nt] = (f32x4){0.f, 0.f, 0.f, 0.f};
        const unsigned short* yrow = hs + (size_t)(w * 16 + l15) * 132 + quad * 8;
#pragma unroll
        for (int k2 = 0; k2 < 4; ++k2) {
            V8 b;
            b.h[0] = *(const short4*)(yrow + k2 * 32);
            b.h[1] = *(const short4*)(yrow + k2 * 32 + 4);
#pragma unroll
            for (int nt = 0; nt < 4; ++nt) {
                const unsigned short* ar = wsd + (size_t)(nt * 16 + l15) * 132
                                           + k2 * 32 + quad * 8;
                V8 av;
                av.h[0] = *(const short4*)ar;
                av.h[1] = *(const short4*)(ar + 4);
                acc[nt] = __builtin_amdgcn_mfma_f32_16x16x32_bf16(av.v, b.v, acc[nt], 0, 0, 0);
            }
        }
        // per-wave transpose through private ts region (no extra barrier)
        unsigned short* tw = ts + w * 16 * 68;
#pragma unroll
        for (int nt = 0; nt < 4; ++nt) {
            int c0 = nt * 16 + quad * 4;
            uint2 o = make_uint2(f2b2(acc[nt][0], acc[nt][1]),
                                 f2b2(acc[nt][2], acc[nt][3]));
            *(uint2*)&tw[l15 * 68 + c0] = o;
        }
        // readback + coalesced global store: 2 instrs of 16B/lane
#pragma unroll
        for (int jj = 0; jj < 2; ++jj) {
            int rl = (lane >> 3) + 8 * jj;
            int off = (lane & 7) * 8;
            int g = n0 + w * 16 + rl;
            V8 v;
            v.h[0] = *(const short4*)&tw[rl * 68 + off];
            v.h[1] = *(const short4*)&tw[rl * 68 + off + 4];
            if (g < N)
                *(bf16x8*)(proj2 + ((size_t)r * N + g) * 64 + off) = v.v;
        }
        __syncthreads();
    }
}

// =====================================================================
// gather_out2 (layer 2): out[n] = sum_{e in(n)} w_premul * proj2[r][src]
//                                 + proj2[8][n] + bias      (f32 out)
// =====================================================================
__global__ __launch_bounds__(256) void gather_out2(
    const int* __restrict__ rp2, const int* __restrict__ bsum,
    const unsigned* __restrict__ erec,
    const unsigned short* __restrict__ proj2,   // 9 x N x 64 bf16
    const float* __restrict__ bias,
    float* __restrict__ out, int N)
{
    int gid = blockIdx.x * 256 + threadIdx.x;
    int n = gid >> 3;
    if (n >= N) return;
    int j = (gid & 7) * 8;

    int base = n * R_NUM;
    int bs_n = bsum[base >> 11];
    int4 ea = *(const int4*)(rp2 + base);
    int4 eb = *(const int4*)(rp2 + base + 4);
    int ends[8] = {ea.x + bs_n, ea.y + bs_n, ea.z + bs_n, ea.w + bs_n,
                   eb.x + bs_n, eb.y + bs_n, eb.z + bs_n, eb.w + bs_n};
    int k = (n == 0) ? 0 : rp2[base - 1] + bsum[(base - 1) >> 11];

    float acc[8] = {0.f, 0.f, 0.f, 0.f, 0.f, 0.f, 0.f, 0.f};
#pragma unroll
    for (int r = 0; r < 8; ++r) {
        int end = ends[r];
        for (; k < end; ++k) {
            unsigned rec = erec[k];
            float wgt = __uint_as_float((rec >> 1) & 0x7FFF8000u);
            u16x8 v = *(const u16x8*)(proj2 + ((size_t)r * N + (rec & 0x1FFFFu)) * 64 + j);
#pragma unroll
            for (int c = 0; c < 8; ++c) acc[c] += wgt * b2f(v[c]);
        }
    }
    // self/root + bias
    u16x8 sv = *(const u16x8*)(proj2 + ((size_t)8 * N + n) * 64 + j);
    float4 b0 = *(const float4*)(bias + j);
    float4 b1 = *(const float4*)(bias + j + 4);
    float* o = out + (size_t)n * 64 + j;
    o[0] = acc[0] + b2f(sv[0]) + b0.x;
    o[1] = acc[1] + b2f(sv[1]) + b0.y;
    o[2] = acc[2] + b2f(sv[2]) + b0.z;
    o[3] = acc[3] + b2f(sv[3]) + b0.w;
    o[4] = acc[4] + b2f(sv[4]) + b1.x;
    o[5] = acc[5] + b2f(sv[5]) + b1.y;
    o[6] = acc[6] + b2f(sv[6]) + b1.z;
    o[7] = acc[7] + b2f(sv[7]) + b1.w;
}

extern "C" void kernel_launch(void* const* d_in, const int* in_sizes, int n_in,
                              void* d_out, int out_size, void* d_ws, size_t ws_size,
                              hipStream_t stream) {
    const float* x     = (const float*)d_in[0];
    const int*   ei    = (const int*)d_in[1];
    const float* ew    = (const float*)d_in[2];
    const int*   et    = (const int*)d_in[3];
    const float* W1    = (const float*)d_in[4];
    const float* root1 = (const float*)d_in[5];
    const float* bias1 = (const float*)d_in[6];
    const float* W2    = (const float*)d_in[7];
    const float* root2 = (const float*)d_in[8];
    const float* bias2 = (const float*)d_in[9];

    const int N = in_sizes[0] / F_DIM;
    const int E = in_sizes[2];
    const int M2 = N * R_NUM;
    const int* srcp = ei;
    const int* dstp = ei + E;

    // ws layout (int units unless noted):
    // mm[16] | invc[N] | deg2[8N] | rp2[8N] | bsum[256] | bmn[512] | bmx[512] |
    // erec[E] | xb[N*128 u16] | hb[N*128 u16] | wt1[9*128*128 u16] |
    // wt2[9*64*128 u16] | y[8*N*128 u16, r-major] (proj2 aliases y)
    int* base = (int*)d_ws;
    float* mm    = (float*)base;
    float* invc  = (float*)(base + 16);
    int*   deg2  = base + 16 + N;
    int*   rp2   = deg2 + M2;
    int*   bsum  = rp2 + M2;
    float* bmn   = (float*)(bsum + 256);
    float* bmx   = bmn + 512;
    unsigned* erec = (unsigned*)(bmx + 512);
    unsigned short* xb  = (unsigned short*)(erec + E);
    unsigned short* hb  = xb + (size_t)N * 128;
    unsigned short* wt1 = hb + (size_t)N * 128;
    unsigned short* wt2 = wt1 + 9 * 128 * 128;
    unsigned short* y   = wt2 + 9 * 64 * 128;   // 8 * N * 128 (r-major)
    unsigned short* proj2 = y;                  // 9 * N * 64 (aliases y)

    const int TB = 256;
    int blocksE = (E + TB - 1) / TB;
    int nb = (M2 + 2047) / 2048;   // 196 <= 256
    long x4 = (long)N * 128 / 4;

    // ---- setup ----
    (void)hipMemsetAsync(deg2, 0, (size_t)M2 * sizeof(int), stream);
    setupA<<<512, TB, 0, stream>>>(ew, dstp, et, E, deg2, bmn, bmx,
                                   x, xb, x4, W1, root1, W2, root2, wt1, wt2);
    scan1_kernel<<<nb, TB, 0, stream>>>(deg2, rp2, bsum, invc, M2, N);
    scan2_mm<<<1, TB, 0, stream>>>(bsum, nb, bmn, bmx, mm);
    fill2_kernel<<<blocksE, TB, 0, stream>>>(srcp, dstp, et, ew, mm, invc,
                                             rp2, bsum, erec, E);

    int gatB = (int)(((long)M2 * 16 + TB - 1) / TB);   // 25000
    int gB1 = (N + 127) / 128;                         // 391

    // ---- layer 1 (aggregate-first): gather y ; gemm -> hb (bf16, relu) ----
    gather_y<<<gatB, TB, 0, stream>>>(rp2, bsum, erec, xb, y, N);
    gemm_y2<<<gB1, 512, 0, stream>>>(y, xb, wt1, bias1, hb, N);

    // ---- layer 2 (transform-first): proj2 = h@W2[r] (fat tile) ;
    //      gather -> out ----
    gemm_proj2<<<gB1, 512, 0, stream>>>(hb, wt2, proj2, N);
    int g2B = (int)(((long)N * 8 + TB - 1) / TB);      // 1563
    gather_out2<<<g2B, TB, 0, stream>>>(rp2, bsum, erec, proj2, bias2,
                                        (float*)d_out, N);
}

// Round 13
// 281.927 us; speedup vs baseline: 1.0255x; 1.0255x over previous
//
#include <hip/hip_runtime.h>
#include <hip/hip_bf16.h>

// Problem constants: N=50000, E=600000, F=128, H=128, O=64, R=8
#define F_DIM 128
#define H_DIM 128
#define O_DIM 64
#define R_NUM 8

typedef __attribute__((ext_vector_type(8))) short bf16x8;
typedef __attribute__((ext_vector_type(4))) float f32x4;
typedef __attribute__((ext_vector_type(8))) unsigned short u16x8;

union V8 { bf16x8 v; short4 h[2]; };

__device__ __forceinline__ unsigned short f2b(float f) {
    unsigned u = __float_as_uint(f);
    u += 0x7FFFu + ((u >> 16) & 1u);   // RNE (manual; kept for fill2 only)
    return (unsigned short)(u >> 16);
}
// HW RNE pair-convert (v_cvt_pk_bf16_f32), bit-identical to manual RNE.
__device__ __forceinline__ unsigned f2b2(float lo, float hi) {
    union { __hip_bfloat162 h; unsigned u; } p;
    p.h = __float22bfloat162_rn(make_float2(lo, hi));
    return p.u;
}
__device__ __forceinline__ unsigned short f2b1(float f) {
    union { __hip_bfloat16 h; unsigned short u; } p;
    p.h = __float2bfloat16(f);
    return p.u;
}
__device__ __forceinline__ float b2f(unsigned short b) {
    return __uint_as_float(((unsigned)b) << 16);
}

// ---- fused setup A: (dst,rel) degree count + per-block ew min/max ;
//      x -> bf16 ; both weight stacks transpose+convert. Grid MUST be 512. ----
__global__ __launch_bounds__(256) void setupA(
    const float* __restrict__ ew, const int* __restrict__ dst,
    const int* __restrict__ et, int E, int* __restrict__ deg2,
    float* __restrict__ bmn, float* __restrict__ bmx,
    const float* __restrict__ x, unsigned short* __restrict__ xb, long x4,
    const float* __restrict__ W1, const float* __restrict__ root1,
    const float* __restrict__ W2, const float* __restrict__ root2,
    unsigned short* __restrict__ wt1, unsigned short* __restrict__ wt2) {
    __shared__ float smn[256], smx[256];
    const int tid = threadIdx.x;
    const int gstride = gridDim.x * blockDim.x;
    int g0 = blockIdx.x * blockDim.x + tid;

    float mn = 1e30f, mx = -1e30f;
    for (int i = g0; i < E; i += gstride) {
        atomicAdd(&deg2[dst[i] * R_NUM + et[i]], 1);
        float v = ew[i];
        mn = fminf(mn, v);
        mx = fmaxf(mx, v);
    }
    smn[tid] = mn; smx[tid] = mx;
    __syncthreads();
    for (int s = 128; s > 0; s >>= 1) {
        if (tid < s) {
            smn[tid] = fminf(smn[tid], smn[tid + s]);
            smx[tid] = fmaxf(smx[tid], smx[tid + s]);
        }
        __syncthreads();
    }
    if (tid == 0) { bmn[blockIdx.x] = smn[0]; bmx[blockIdx.x] = smx[0]; }

    for (long i = g0; i < x4; i += gstride) {
        float4 v = ((const float4*)x)[i];
        uint2 o = make_uint2(f2b2(v.x, v.y), f2b2(v.z, v.w));
        ((uint2*)xb)[i] = o;
    }

    const int n1 = 9 * 128 * 128, n2 = 9 * 64 * 128;
    for (int idx = g0; idx < n1 + n2; idx += gstride) {
        if (idx < n1) {
            int r = idx / (128 * 128), rem = idx % (128 * 128);
            int n = rem / 128, k = rem % 128;
            float v = (r < 8) ? W1[((size_t)r * 128 + k) * 128 + n]
                              : root1[(size_t)k * 128 + n];
            wt1[idx] = f2b1(v);
        } else {
            int j = idx - n1;
            int r = j / (64 * 128), rem = j % (64 * 128);
            int n = rem / 128, k = rem % 128;
            float v = (r < 8) ? W2[((size_t)r * 128 + k) * 64 + n]
                              : root2[(size_t)k * 64 + n];
            wt2[j] = f2b1(v);
        }
    }
}

// ---- scan1: per-2048-chunk exclusive scan of deg2 + fused invc ----
__global__ void scan1_kernel(const int* __restrict__ deg, int* __restrict__ rp,
                             int* __restrict__ bsum, float* __restrict__ invc,
                             int M, int N) {
    __shared__ int s[256];
    int base = blockIdx.x * 2048;
    int t = threadIdx.x;
    int v[8]; int loc = 0;
#pragma unroll
    for (int i = 0; i < 8; ++i) {
        int idx = base + t * 8 + i;
        v[i] = (idx < M) ? deg[idx] : 0;
        loc += v[i];
    }
    int node = blockIdx.x * 256 + t;
    if (node < N) invc[node] = 1.0f / (float)max(loc, 1);
    s[t] = loc;
    __syncthreads();
    for (int off = 1; off < 256; off <<= 1) {
        int x = (t >= off) ? s[t - off] : 0;
        __syncthreads();
        s[t] += x;
        __syncthreads();
    }
    int run = s[t] - loc;
#pragma unroll
    for (int i = 0; i < 8; ++i) {
        int idx = base + t * 8 + i;
        if (idx < M) rp[idx] = run;
        run += v[i];
    }
    if (t == 255) bsum[blockIdx.x] = s[255];
}

// ---- scan2 + global min/max reduce (single block) ----
// After this, rp2 stays CHUNK-LOCAL; consumers add bsum[i>>11].
__global__ void scan2_mm(int* bsum, int nb, const float* __restrict__ bmn,
                         const float* __restrict__ bmx, float* mm) {
    __shared__ int s[256];
    __shared__ float smn[256], smx[256];
    int t = threadIdx.x;
    int v = (t < nb) ? bsum[t] : 0;
    s[t] = v;
    smn[t] = fminf(bmn[t], bmn[t + 256]);
    smx[t] = fmaxf(bmx[t], bmx[t + 256]);
    __syncthreads();
    for (int off = 1; off < 256; off <<= 1) {
        int x = (t >= off) ? s[t - off] : 0;
        __syncthreads();
        s[t] += x;
        __syncthreads();
    }
    if (t < nb) bsum[t] = s[t] - v;
    for (int r = 128; r > 0; r >>= 1) {
        if (t < r) {
            smn[t] = fminf(smn[t], smn[t + r]);
            smx[t] = fmaxf(smx[t], smx[t + r]);
        }
        __syncthreads();
    }
    if (t == 0) { mm[0] = smn[0]; mm[1] = smx[0]; }
}

// ---- CSR fill: pos = (rp2[i]++ local) + bsum[i>>11] ;
//      erec = bf16(w_norm * invc[dst])<<17 | src   (4B record)
__global__ void fill2_kernel(const int* __restrict__ src, const int* __restrict__ dst,
                             const int* __restrict__ et, const float* __restrict__ ew,
                             const float* __restrict__ mm, const float* __restrict__ invc,
                             int* __restrict__ rp2, const int* __restrict__ bsum,
                             unsigned* __restrict__ erec, int E) {
    int e = blockIdx.x * blockDim.x + threadIdx.x;
    if (e >= E) return;
    int d = dst[e];
    int i = d * R_NUM + et[e];
    int pos = atomicAdd(&rp2[i], 1) + bsum[i >> 11];
    float mn = mm[0], mx = mm[1];
    unsigned wq = f2b((ew[e] - mn) / (mx - mn + 1e-8f) * invc[d]);
    erec[pos] = (wq << 17) | (unsigned)src[e];
}

// ---- gather (layer 1): y[r][n] = sum_{e in seg(n,r)} w_premul * inp[src]
//      y layout R-MAJOR [r][N][128]. Epilogue uses HW cvt_pk. ----
__global__ __launch_bounds__(256) void gather_y(
    const int* __restrict__ rp2, const int* __restrict__ bsum,
    const unsigned* __restrict__ erec,
    const unsigned short* __restrict__ inp,
    unsigned short* __restrict__ y, int N) {
    int gid = blockIdx.x * 256 + threadIdx.x;
    int seg = gid >> 4;
    int n = seg >> 3;
    if (n >= N) return;
    int j = (gid & 15) * 8;
    int beg = (seg == 0) ? 0 : rp2[seg - 1] + bsum[(seg - 1) >> 11];
    int end = rp2[seg] + bsum[seg >> 11];
    float acc[8] = {0.f, 0.f, 0.f, 0.f, 0.f, 0.f, 0.f, 0.f};
    int k = beg;
    for (; k + 2 <= end; k += 2) {
        unsigned r0 = erec[k], r1 = erec[k + 1];
        float w0 = __uint_as_float((r0 >> 1) & 0x7FFF8000u);
        float w1 = __uint_as_float((r1 >> 1) & 0x7FFF8000u);
        u16x8 v0 = *(const u16x8*)(inp + (size_t)(r0 & 0x1FFFFu) * 128 + j);
        u16x8 v1 = *(const u16x8*)(inp + (size_t)(r1 & 0x1FFFFu) * 128 + j);
#pragma unroll
        for (int c = 0; c < 8; ++c) acc[c] += w0 * b2f(v0[c]);
#pragma unroll
        for (int c = 0; c < 8; ++c) acc[c] += w1 * b2f(v1[c]);
    }
    if (k < end) {
        unsigned r0 = erec[k];
        float w0 = __uint_as_float((r0 >> 1) & 0x7FFF8000u);
        u16x8 v0 = *(const u16x8*)(inp + (size_t)(r0 & 0x1FFFFu) * 128 + j);
#pragma unroll
        for (int c = 0; c < 8; ++c) acc[c] += w0 * b2f(v0[c]);
    }
    uint4 ov = make_uint4(f2b2(acc[0], acc[1]), f2b2(acc[2], acc[3]),
                          f2b2(acc[4], acc[5]), f2b2(acc[6], acc[7]));
    // r-major: y[(seg&7)*N + n]
    *(uint4*)(y + ((size_t)(seg & 7) * N + (size_t)n) * 128 + j) = ov;
}

// =====================================================================
// gemm_y2 (layer 1, FAT TILE): out = sum_r y[r][n]@Wt[r] + inp@Wt[8]
// + bias. 128 nodes/block, 512 threads (8 waves); wave w owns output
// cols w*16..w*16+15 x all 128 nodes. A-fragments straight from
// L2-resident wt1 (no LDS, loaded pre-barrier so L2 latency hides under
// barrier skew). 33.8 KB y-tile LDS-staged, double-buffered with RAW
// s_barrier. 2 blocks/CU = 16 waves/CU. (Round-11 best structure;
// round-12's 2-deep register prefetch regressed and is reverted.)
// Race check: buf[r&1] rewritten at iter r+2, after barrier(r+1);
// all iter-r reads of buf[r&1] completed before each wave reached
// barrier(r+1) (lgkm waited before MFMA consumption).
// =====================================================================
__global__ __launch_bounds__(512, 4) void gemm_y2(
    const unsigned short* __restrict__ y,        // 8 x N x 128 bf16 (r-major)
    const unsigned short* __restrict__ inp,      // xb: N x 128 bf16
    const unsigned short* __restrict__ Wt,       // 9 x 128 x 128 bf16
    const float* __restrict__ bias,
    unsigned short* __restrict__ outb, int N)
{
    __shared__ unsigned short smem[2 * 128 * 132];   // 2 x (128 x 132) y bufs

    const int tid = threadIdx.x;
    const int w = tid >> 6, lane = tid & 63;         // w in 0..7
    const int quad = lane >> 4, l15 = lane & 15;
    const int n0 = blockIdx.x * 128;

    // per-thread staging slots: 4 chunks of 16B (128 rows x 16 segs / 512 thr)
    V8 st[4];
    int srow[4], sseg[4];
#pragma unroll
    for (int it = 0; it < 4; ++it) {
        int u = tid + it * 512;
        srow[it] = u >> 4;          // 0..127
        sseg[it] = u & 15;
    }

    // issue global loads for tile r into st regs (r==8 -> root/xb)
    auto issue = [&](int r) {
#pragma unroll
        for (int it = 0; it < 4; ++it) {
            int node = n0 + srow[it];
            if (node >= N) node = N - 1;
            const unsigned short* src = (r < 8)
                ? y + ((size_t)r * N + (size_t)node) * 128 + sseg[it] * 8
                : inp + (size_t)node * 128 + sseg[it] * 8;
            st[it].v = *(const bf16x8*)src;
        }
    };

    f32x4 acc[8];
#pragma unroll
    for (int g = 0; g < 8; ++g) acc[g] = (f32x4){0.f, 0.f, 0.f, 0.f};

    issue(0);

    for (int r = 0; r < 9; ++r) {
        unsigned short* ysb = smem + (r & 1) * (128 * 132);
        // write staged tile r to LDS (compiler waits vmcnt for st deps)
#pragma unroll
        for (int it = 0; it < 4; ++it) {
            *(short4*)&ysb[srow[it] * 132 + sseg[it] * 8]     = st[it].h[0];
            *(short4*)&ysb[srow[it] * 132 + sseg[it] * 8 + 4] = st[it].h[1];
        }
        // prefetch next tile: stays in flight across the RAW barrier
        if (r < 8) issue(r + 1);
        // A-fragments (this wave's 16-col slice), straight from L2,
        // issued pre-barrier so latency overlaps barrier wait
        const unsigned short* wbase = Wt + (size_t)r * 128 * 128;
        bf16x8 afr[4];
#pragma unroll
        for (int k2 = 0; k2 < 4; ++k2) {
            afr[k2] = *(const bf16x8*)(wbase
                + (size_t)(w * 16 + l15) * 128 + k2 * 32 + quad * 8);
        }
        asm volatile("s_waitcnt lgkmcnt(0)" ::: "memory");
        __builtin_amdgcn_s_barrier();

#pragma unroll
        for (int k2 = 0; k2 < 4; ++k2) {
#pragma unroll
            for (int g = 0; g < 8; ++g) {
                const unsigned short* yr = ysb + (size_t)(g * 16 + l15) * 132
                                           + k2 * 32 + quad * 8;
                V8 b;
                b.h[0] = *(const short4*)yr;
                b.h[1] = *(const short4*)(yr + 4);
                acc[g] = __builtin_amdgcn_mfma_f32_16x16x32_bf16(afr[k2], b.v, acc[g], 0, 0, 0);
            }
        }
        // no trailing barrier: next iteration's ds_writes go to the other
        // buffer; overwrite of THIS buffer is 2 barriers away
    }

    __syncthreads();   // all MFMA reads done before stg overwrites smem
    unsigned short* stg = smem;   // 128 x 136 (34.8 KB, fits)
    {
        const int c0 = w * 16 + quad * 4;
        float4 bs = *(const float4*)(bias + c0);
#pragma unroll
        for (int g = 0; g < 8; ++g) {
            float v0 = acc[g][0] + bs.x, v1 = acc[g][1] + bs.y;
            float v2 = acc[g][2] + bs.z, v3 = acc[g][3] + bs.w;
            v0 = fmaxf(v0, 0.f); v1 = fmaxf(v1, 0.f);
            v2 = fmaxf(v2, 0.f); v3 = fmaxf(v3, 0.f);
            uint2 o = make_uint2(f2b2(v0, v1), f2b2(v2, v3));
            *(uint2*)&stg[(g * 16 + l15) * 136 + c0] = o;
        }
    }
    __syncthreads();
    const int gn = tid >> 2, gq = tid & 3;   // gn 0..127
    const int gnode = n0 + gn;
    if (gnode < N) {
        const unsigned short* srw = stg + gn * 136 + gq * 32;
        unsigned short* drow = outb + (size_t)gnode * 128 + gq * 32;
#pragma unroll
        for (int c = 0; c < 4; ++c)
            *(bf16x8*)(drow + c * 8) = *(const bf16x8*)(srw + c * 8);
    }
}

// =====================================================================
// gemm_proj2 (layer 2 transform-first, FAT TILE): proj2[r][n][c] =
// h[n] @ W2t[r], r=0..8 (r=8 = root). 128 nodes/block, 512 threads
// (8 waves); wave w owns nodes w*16..+15 x all 64 cols. (Round-11
// passing structure, unchanged.)
// =====================================================================
__global__ __launch_bounds__(512) void gemm_proj2(
    const unsigned short* __restrict__ h,     // N x 128 bf16
    const unsigned short* __restrict__ Wt,    // 9 x 64 x 128 bf16
    unsigned short* __restrict__ proj2,       // 9 x N x 64 bf16
    int N)
{
    __shared__ unsigned short hs[128 * 132];
    __shared__ unsigned short wsd[64 * 132];
    __shared__ unsigned short ts[8 * 16 * 68];   // per-wave private 16x68

    const int tid = threadIdx.x;
    const int w = tid >> 6, lane = tid & 63;     // w in 0..7
    const int quad = lane >> 4, l15 = lane & 15;
    const int n0 = blockIdx.x * 128;

    // stage h slice once (128 nodes x 128)
#pragma unroll
    for (int it = 0; it < 4; ++it) {
        int u = tid + it * 512;
        int row = u >> 4, seg = u & 15;
        int node = n0 + row;
        if (node >= N) node = N - 1;
        V8 v; v.v = *(const bf16x8*)(h + (size_t)node * 128 + seg * 8);
        *(short4*)&hs[row * 132 + seg * 8]     = v.h[0];
        *(short4*)&hs[row * 132 + seg * 8 + 4] = v.h[1];
    }

    for (int r = 0; r < 9; ++r) {
        // stage W2t[r] (64 rows x 128) with 512 threads (2 its)
#pragma unroll
        for (int it = 0; it < 2; ++it) {
            int u = tid + it * 512;
            int row = u >> 4, seg = u & 15;
            V8 v;
            v.v = *(const bf16x8*)(Wt + ((size_t)r * 64 + row) * 128 + seg * 8);
            *(short4*)&wsd[row * 132 + seg * 8]     = v.h[0];
            *(short4*)&wsd[row * 132 + seg * 8 + 4] = v.h[1];
        }
        __syncthreads();
        // MFMA: wave w -> nodes w*16..+15, 64 cols (NT=4)
        f32x4 acc[4];
#pragma unroll
        for (int nt = 0; nt < 4; ++nt) acc[nt] = (f32x4){0.f, 0.f, 0.f, 0.f};
        const unsigned short* yrow = hs + (size_t)(w * 16 + l15) * 132 + quad * 8;
#pragma unroll
        for (int k2 = 0; k2 < 4; ++k2) {
            V8 b;
            b.h[0] = *(const short4*)(yrow + k2 * 32);
            b.h[1] = *(const short4*)(yrow + k2 * 32 + 4);
#pragma unroll
            for (int nt = 0; nt < 4; ++nt) {
                const unsigned short* ar = wsd + (size_t)(nt * 16 + l15) * 132
                                           + k2 * 32 + quad * 8;
                V8 av;
                av.h[0] = *(const short4*)ar;
                av.h[1] = *(const short4*)(ar + 4);
                acc[nt] = __builtin_amdgcn_mfma_f32_16x16x32_bf16(av.v, b.v, acc[nt], 0, 0, 0);
            }
        }
        // per-wave transpose through private ts region (no extra barrier)
        unsigned short* tw = ts + w * 16 * 68;
#pragma unroll
        for (int nt = 0; nt < 4; ++nt) {
            int c0 = nt * 16 + quad * 4;
            uint2 o = make_uint2(f2b2(acc[nt][0], acc[nt][1]),
                                 f2b2(acc[nt][2], acc[nt][3]));
            *(uint2*)&tw[l15 * 68 + c0] = o;
        }
        // readback + coalesced global store: 2 instrs of 16B/lane
#pragma unroll
        for (int jj = 0; jj < 2; ++jj) {
            int rl = (lane >> 3) + 8 * jj;
            int off = (lane & 7) * 8;
            int g = n0 + w * 16 + rl;
            V8 v;
            v.h[0] = *(const short4*)&tw[rl * 68 + off];
            v.h[1] = *(const short4*)&tw[rl * 68 + off + 4];
            if (g < N)
                *(bf16x8*)(proj2 + ((size_t)r * N + g) * 64 + off) = v.v;
        }
        __syncthreads();
    }
}

// =====================================================================
// gather_out2 (layer 2): out[n] = sum_{e in(n)} w_premul * proj2[r][src]
//                                 + proj2[8][n] + bias      (f32 out)
// =====================================================================
__global__ __launch_bounds__(256) void gather_out2(
    const int* __restrict__ rp2, const int* __restrict__ bsum,
    const unsigned* __restrict__ erec,
    const unsigned short* __restrict__ proj2,   // 9 x N x 64 bf16
    const float* __restrict__ bias,
    float* __restrict__ out, int N)
{
    int gid = blockIdx.x * 256 + threadIdx.x;
    int n = gid >> 3;
    if (n >= N) return;
    int j = (gid & 7) * 8;

    int base = n * R_NUM;
    int bs_n = bsum[base >> 11];
    int4 ea = *(const int4*)(rp2 + base);
    int4 eb = *(const int4*)(rp2 + base + 4);
    int ends[8] = {ea.x + bs_n, ea.y + bs_n, ea.z + bs_n, ea.w + bs_n,
                   eb.x + bs_n, eb.y + bs_n, eb.z + bs_n, eb.w + bs_n};
    int k = (n == 0) ? 0 : rp2[base - 1] + bsum[(base - 1) >> 11];

    float acc[8] = {0.f, 0.f, 0.f, 0.f, 0.f, 0.f, 0.f, 0.f};
#pragma unroll
    for (int r = 0; r < 8; ++r) {
        int end = ends[r];
        for (; k < end; ++k) {
            unsigned rec = erec[k];
            float wgt = __uint_as_float((rec >> 1) & 0x7FFF8000u);
            u16x8 v = *(const u16x8*)(proj2 + ((size_t)r * N + (rec & 0x1FFFFu)) * 64 + j);
#pragma unroll
            for (int c = 0; c < 8; ++c) acc[c] += wgt * b2f(v[c]);
        }
    }
    // self/root + bias
    u16x8 sv = *(const u16x8*)(proj2 + ((size_t)8 * N + n) * 64 + j);
    float4 b0 = *(const float4*)(bias + j);
    float4 b1 = *(const float4*)(bias + j + 4);
    float* o = out + (size_t)n * 64 + j;
    o[0] = acc[0] + b2f(sv[0]) + b0.x;
    o[1] = acc[1] + b2f(sv[1]) + b0.y;
    o[2] = acc[2] + b2f(sv[2]) + b0.z;
    o[3] = acc[3] + b2f(sv[3]) + b0.w;
    o[4] = acc[4] + b2f(sv[4]) + b1.x;
    o[5] = acc[5] + b2f(sv[5]) + b1.y;
    o[6] = acc[6] + b2f(sv[6]) + b1.z;
    o[7] = acc[7] + b2f(sv[7]) + b1.w;
}

extern "C" void kernel_launch(void* const* d_in, const int* in_sizes, int n_in,
                              void* d_out, int out_size, void* d_ws, size_t ws_size,
                              hipStream_t stream) {
    const float* x     = (const float*)d_in[0];
    const int*   ei    = (const int*)d_in[1];
    const float* ew    = (const float*)d_in[2];
    const int*   et    = (const int*)d_in[3];
    const float* W1    = (const float*)d_in[4];
    const float* root1 = (const float*)d_in[5];
    const float* bias1 = (const float*)d_in[6];
    const float* W2    = (const float*)d_in[7];
    const float* root2 = (const float*)d_in[8];
    const float* bias2 = (const float*)d_in[9];

    const int N = in_sizes[0] / F_DIM;
    const int E = in_sizes[2];
    const int M2 = N * R_NUM;
    const int* srcp = ei;
    const int* dstp = ei + E;

    // ws layout (int units unless noted):
    // mm[16] | invc[N] | deg2[8N] | rp2[8N] | bsum[256] | bmn[512] | bmx[512] |
    // erec[E] | xb[N*128 u16] | hb[N*128 u16] | wt1[9*128*128 u16] |
    // wt2[9*64*128 u16] | y[8*N*128 u16, r-major] (proj2 aliases y)
    int* base = (int*)d_ws;
    float* mm    = (float*)base;
    float* invc  = (float*)(base + 16);
    int*   deg2  = base + 16 + N;
    int*   rp2   = deg2 + M2;
    int*   bsum  = rp2 + M2;
    float* bmn   = (float*)(bsum + 256);
    float* bmx   = bmn + 512;
    unsigned* erec = (unsigned*)(bmx + 512);
    unsigned short* xb  = (unsigned short*)(erec + E);
    unsigned short* hb  = xb + (size_t)N * 128;
    unsigned short* wt1 = hb + (size_t)N * 128;
    unsigned short* wt2 = wt1 + 9 * 128 * 128;
    unsigned short* y   = wt2 + 9 * 64 * 128;   // 8 * N * 128 (r-major)
    unsigned short* proj2 = y;                  // 9 * N * 64 (aliases y)

    const int TB = 256;
    int blocksE = (E + TB - 1) / TB;
    int nb = (M2 + 2047) / 2048;   // 196 <= 256
    long x4 = (long)N * 128 / 4;

    // ---- setup ----
    (void)hipMemsetAsync(deg2, 0, (size_t)M2 * sizeof(int), stream);
    setupA<<<512, TB, 0, stream>>>(ew, dstp, et, E, deg2, bmn, bmx,
                                   x, xb, x4, W1, root1, W2, root2, wt1, wt2);
    scan1_kernel<<<nb, TB, 0, stream>>>(deg2, rp2, bsum, invc, M2, N);
    scan2_mm<<<1, TB, 0, stream>>>(bsum, nb, bmn, bmx, mm);
    fill2_kernel<<<blocksE, TB, 0, stream>>>(srcp, dstp, et, ew, mm, invc,
                                             rp2, bsum, erec, E);

    int gatB = (int)(((long)M2 * 16 + TB - 1) / TB);   // 25000
    int gB1 = (N + 127) / 128;                         // 391

    // ---- layer 1 (aggregate-first): gather y ; gemm -> hb (bf16, relu) ----
    gather_y<<<gatB, TB, 0, stream>>>(rp2, bsum, erec, xb, y, N);
    gemm_y2<<<gB1, 512, 0, stream>>>(y, xb, wt1, bias1, hb, N);

    // ---- layer 2 (transform-first): proj2 = h@W2[r] (fat tile) ;
    //      gather -> out ----
    gemm_proj2<<<gB1, 512, 0, stream>>>(hb, wt2, proj2, N);
    int g2B = (int)(((long)N * 8 + TB - 1) / TB);      // 1563
    gather_out2<<<g2B, TB, 0, stream>>>(rp2, bsum, erec, proj2, bias2,
                                        (float*)d_out, N);
}